// Round 2
// baseline (133.165 us; speedup 1.0000x reference)
//
#include <hip/hip_runtime.h>

// TopologyAwareAttention — R11: single-node fully-fused kernel.
// Model: dur = ~40us ws poison fill (harness, 256MiB @83% HBM) + restores +
//        ~7us/node + kernel work. R10 showed the redundant-stats move is free
//        but kept 2 nodes; R11 removes the k1 node entirely by computing the
//        900 argmaxes REDUNDANTLY in every block (0.92MB/block from L2,
//        182MB aggregate ~5.3us, overlapped with the block's full attn HBM
//        read issued first). No workspace, no tags, no polling, no sync.
//  f(t) = sum_e relu(t*w1[e]+b1[e]) * mean_h(w2[e,h]) + mean(b2)
//  centers on 16x16 grid => d2 = dx^2+dy^2 in [0,450] => 451-entry LUT
//  mean dist via cell histogram: sum = SUM_{c1,c2} h[c1] h[c2] sqrt(d2)
// All stats float chains verbatim from R10/R9 (absmax bit-identical).
// Argmax: per-f4 max-tree + first-equal select == exact first-max (strict >
// across f4s keeps earliest group; within-f4 select picks first equal).

#define NQ    900
#define LUT_N 451

// one step of a per-query argmax chain over one float4 (elements 4K..4K+3)
#define ARGSTEP(V, BV, BI, K)                                               \
    {                                                                       \
        float m01_ = fmaxf((V).x, (V).y);                                   \
        float m23_ = fmaxf((V).z, (V).w);                                   \
        float m_   = fmaxf(m01_, m23_);                                     \
        if (m_ > (BV)) {                                                    \
            (BV) = m_;                                                      \
            int kb_ = (K) * 4;                                              \
            (BI) = ((V).x == m_) ? kb_                                      \
                 : ((V).y == m_) ? kb_ + 1                                  \
                 : ((V).z == m_) ? kb_ + 2 : kb_ + 3;                       \
        }                                                                   \
    }

__global__ __launch_bounds__(256)
void k_fused(const float* __restrict__ attn,
             const float* __restrict__ ref,
             const float* __restrict__ lam_p,
             const float* __restrict__ w1,
             const float* __restrict__ b1,
             const float* __restrict__ w2,
             const float* __restrict__ b2,
             float* __restrict__ out) {
    const int tid  = threadIdx.x;
    const int lane = tid & 63;
    const int wave = tid >> 6;
    const int b    = blockIdx.y;

    // ---- phase A: issue the block's ENTIRE attn slice (drains under the
    //      argmax L2 phase). Addresses pure linear in f4. ----
    const float4* attn4 = (const float4*)attn;
    float4*       out4  = (float4*)out;
    const int f4l = blockIdx.x * 2048 + tid;           // batch-local float4 idx
    float4 a[8];
    if (blockIdx.x < 98) {
        #pragma unroll
        for (int u = 0; u < 8; ++u)
            a[u] = attn4[(size_t)b * 202500 + f4l + u * 256];
    } else {
        #pragma unroll
        for (int u = 0; u < 8; ++u)
            if (f4l + u * 256 < 202500)
                a[u] = attn4[(size_t)b * 202500 + f4l + u * 256];
    }

    // ---- phase B: LDS setup + redundant argmax ----
    __shared__ int   cpk[226];                         // packed centers u8x4
    __shared__ int   hsh[256];
    __shared__ float sqs[LUT_N];
    __shared__ float w1s[256], b1s[256], wbars[256];
    __shared__ float lut_s[LUT_N];
    __shared__ float wsum[4];

    hsh[tid] = 0;
    w1s[tid] = w1[tid];
    b1s[tid] = b1[tid];
    {
        float s8 = 0.f;
        #pragma unroll
        for (int h = 0; h < 8; ++h) s8 += w2[tid * 8 + h];
        wbars[tid] = s8 * 0.125f;
    }
    for (int s = tid; s < LUT_N; s += 256) sqs[s] = sqrtf((float)s);

    // thread t < 225 owns queries 4t..4t+3: 4 independent compare chains
    // (ILP hides the cmp->cndmask latency at 1 wave/SIMD), packs one word.
    // Per-thread streams are sequential 16B so each 64B L1 line is consumed
    // within the unroll-4 window; L2 traffic stays at 0.92MB/block.
    if (tid < 225) {
        const float*  rb = ref + ((size_t)b * 900 + (size_t)tid * 4) * 256;
        const float4* r0 = (const float4*)(rb);
        const float4* r1 = (const float4*)(rb + 256);
        const float4* r2 = (const float4*)(rb + 512);
        const float4* r3 = (const float4*)(rb + 768);
        float bv0 = -1e38f, bv1 = -1e38f, bv2 = -1e38f, bv3 = -1e38f;
        int   bi0 = 0, bi1 = 0, bi2 = 0, bi3 = 0;
        #pragma unroll 4
        for (int k = 0; k < 64; ++k) {
            float4 v0 = r0[k], v1 = r1[k], v2 = r2[k], v3 = r3[k];
            ARGSTEP(v0, bv0, bi0, k)
            ARGSTEP(v1, bv1, bi1, k)
            ARGSTEP(v2, bv2, bi2, k)
            ARGSTEP(v3, bv3, bi3, k)
        }
        cpk[tid] = (bi0 & 255)        | ((bi1 & 255) << 8) |
                   ((bi2 & 255) << 16) | ((bi3 & 255) << 24);
    }
    __syncthreads();

    // ---- histogram of cells ----
    for (int k = tid; k < NQ; k += 256) {
        int c = (cpk[k >> 2] >> ((k & 3) * 8)) & 255;
        atomicAdd(&hsh[c], 1);
    }
    __syncthreads();

    // ---- pairwise mean via cell histogram (verbatim) ----
    float local = 0.f;
    {
        int h2v = hsh[tid];                            // thread owns c2 = tid
        if (h2v) {
            int ix2 = tid & 15, iy2 = tid >> 4;
            for (int c1 = 0; c1 < 256; ++c1) {
                int h1 = hsh[c1];                      // broadcast read
                int dx = (c1 & 15) - ix2;
                int dy = (c1 >> 4) - iy2;
                local += (float)h1 * sqs[dx * dx + dy * dy];
            }
            local *= (float)h2v;
        }
    }
    #pragma unroll
    for (int off = 32; off >= 1; off >>= 1) local += __shfl_down(local, off, 64);
    if (lane == 0) wsum[wave] = local;
    __syncthreads();

    float tot   = wsum[0] + wsum[1] + wsum[2] + wsum[3];
    float mean  = tot * (1.f / 15.f) * (1.f / ((float)NQ * (float)NQ));
    float inv   = 1.f / (mean + 1e-6f);
    float b2bar = 0.125f * (b2[0] + b2[1] + b2[2] + b2[3] +
                            b2[4] + b2[5] + b2[6] + b2[7]);
    float lam   = lam_p[0];

    // ---- LUT: entries tid and tid+256, interleaved loop (verbatim) ----
    {
        float t0   = sqs[tid] * (1.f / 15.f) * inv;
        bool  has1 = (tid + 256 < LUT_N);              // tid < 195
        float t1   = has1 ? sqs[tid + 256] * (1.f / 15.f) * inv : 0.f;
        float acc0 = b2bar, acc1 = b2bar;
        for (int i = 0; i < 256; ++i) {
            float w  = w1s[i];
            float bb = b1s[i];
            float wb = wbars[i];
            float h0 = fmaf(t0, w, bb);
            acc0 = fmaf(fmaxf(h0, 0.f), wb, acc0);
            float h1 = fmaf(t1, w, bb);
            acc1 = fmaf(fmaxf(h1, 0.f), wb, acc1);
        }
        lut_s[tid] = lam * acc0;
        if (has1) lut_s[tid + 256] = lam * acc1;
    }
    __syncthreads();

    // ---- phase D: apply + store (verbatim) ----
    #pragma unroll
    for (int u = 0; u < 8; ++u) {
        int f4 = f4l + u * 256;
        if (f4 < 202500) {
            int i  = (int)((unsigned)f4 / 225u);       // row 0..899
            int j4 = f4 - i * 225;                     // float4 within row
            int ci = (cpk[i >> 2] >> ((i & 3) * 8)) & 255;   // mostly broadcast
            int ixi = ci & 15, iyi = ci >> 4;
            int cw = cpk[j4];                          // stride-1, conflict-free
            float4 v = a[u];
            int c, dx, dy;
            c = cw & 255;         dx = ixi - (c & 15); dy = iyi - (c >> 4); v.x += lut_s[dx*dx + dy*dy];
            c = (cw >> 8) & 255;  dx = ixi - (c & 15); dy = iyi - (c >> 4); v.y += lut_s[dx*dx + dy*dy];
            c = (cw >> 16) & 255; dx = ixi - (c & 15); dy = iyi - (c >> 4); v.z += lut_s[dx*dx + dy*dy];
            c = (cw >> 24) & 255; dx = ixi - (c & 15); dy = iyi - (c >> 4); v.w += lut_s[dx*dx + dy*dy];
            out4[(size_t)b * 202500 + f4] = v;
        }
    }
}

extern "C" void kernel_launch(void* const* d_in, const int* in_sizes, int n_in,
                              void* d_out, int out_size, void* d_ws, size_t ws_size,
                              hipStream_t stream) {
    const float* attn = (const float*)d_in[0];   // [2,900,900]
    const float* ref  = (const float*)d_in[1];   // [2,900,16,16]
    const float* lam  = (const float*)d_in[2];
    const float* w1   = (const float*)d_in[3];   // [256]
    const float* b1   = (const float*)d_in[4];   // [256]
    const float* w2   = (const float*)d_in[5];   // [256,8]
    const float* b2   = (const float*)d_in[6];   // [8]
    float* out = (float*)d_out;
    (void)d_ws; (void)ws_size;                   // no workspace needed

    k_fused<<<dim3(99, 2), 256, 0, stream>>>(attn, ref, lam, w1, b1, w2, b2, out);
}